// Round 9
// baseline (374.366 us; speedup 1.0000x reference)
//
#include <hip/hip_runtime.h>
#include <hip/hip_bf16.h>
#include <stdint.h>

typedef __attribute__((ext_vector_type(8))) short short8;
typedef __attribute__((ext_vector_type(4))) float f32x4;

__device__ __forceinline__ f32x4 mfma16(short8 a, short8 b, f32x4 c){
  return __builtin_amdgcn_mfma_f32_16x16x32_bf16(a, b, c, 0, 0, 0);
}

union BF8 { short8 v; __hip_bfloat16 h[8]; };

__device__ __forceinline__ void gld_lds16(const void* g, void* l){
  __builtin_amdgcn_global_load_lds((const __attribute__((address_space(1))) void*)g,
                                   (__attribute__((address_space(3))) void*)l, 16, 0, 0);
}

struct GemmDesc { const __hip_bfloat16* A; const __hip_bfloat16* W; const float* bias; void* out; int M; float scale; };
struct GemmArgs { GemmDesc d[6]; };
struct PrepWArgs { const float* src[8]; };
struct CvtArgs { const float* src[4]; __hip_bfloat16* dst[4]; int n[4]; };

// ---------------- f32 -> bf16 elementwise convert ----------------
__global__ __launch_bounds__(256) void cvt_k(CvtArgs c){
  int z = blockIdx.z;
  int n = c.n[z];
  int i = (blockIdx.x * 256 + threadIdx.x) * 8;
  if (i >= n) return;
  const float4* s = (const float4*)(c.src[z] + i);
  float4 u0 = s[0], u1 = s[1];
  BF8 cv;
  cv.h[0] = __float2bfloat16(u0.x); cv.h[1] = __float2bfloat16(u0.y);
  cv.h[2] = __float2bfloat16(u0.z); cv.h[3] = __float2bfloat16(u0.w);
  cv.h[4] = __float2bfloat16(u1.x); cv.h[5] = __float2bfloat16(u1.y);
  cv.h[6] = __float2bfloat16(u1.z); cv.h[7] = __float2bfloat16(u1.w);
  *(short8*)(c.dst[z] + i) = cv.v;
}

// ---------------- weight transpose + cast: Wt[n][k] = bf16(W[k][n]) ----------------
__global__ __launch_bounds__(256) void prep_w_k(PrepWArgs pa, __hip_bfloat16* dst){
  __shared__ float t[64][65];
  const float* W = pa.src[blockIdx.z];
  int k0 = blockIdx.y * 64, n0 = blockIdx.x * 64;
  int c = threadIdx.x & 63, r0 = (threadIdx.x >> 6) * 16;
  #pragma unroll
  for (int i = 0; i < 16; ++i) t[r0 + i][c] = W[(size_t)(k0 + r0 + i) * 1024 + n0 + c];
  __syncthreads();
  __hip_bfloat16* D = dst + (size_t)blockIdx.z * 1048576;
  #pragma unroll
  for (int i = 0; i < 16; ++i) D[(size_t)(n0 + r0 + i) * 1024 + k0 + c] = __float2bfloat16(t[c][r0 + i]);
}

// ---------------- V transpose (bf16): Vt[bh][d][l] = v[bh][l][d] ----------------
__global__ __launch_bounds__(256) void prep_v_k(const __hip_bfloat16* vw, const __hip_bfloat16* vs,
                                                __hip_bfloat16* vtw, __hip_bfloat16* vts){
  bool word = (blockIdx.z == 0);
  int L = word ? 1024 : 256;
  if (!word && blockIdx.x >= 4) return;
  __shared__ __hip_bfloat16 t[64][65];
  const __hip_bfloat16* src = (word ? vw : vs) + (size_t)blockIdx.y * L * 64;
  __hip_bfloat16* dst = (word ? vtw : vts) + (size_t)blockIdx.y * L * 64;
  int l0 = blockIdx.x * 64;
  int c = threadIdx.x & 63, r0 = (threadIdx.x >> 6) * 16;
  #pragma unroll
  for (int i = 0; i < 16; ++i) t[r0 + i][c] = src[(size_t)(l0 + r0 + i) * 64 + c];
  __syncthreads();
  #pragma unroll
  for (int i = 0; i < 16; ++i) dst[(size_t)(r0 + i) * L + l0 + c] = t[c][r0 + i];
}

// ---------------- batched GEMM, m97 structure (unchanged) ----------------
template<bool OUT_BF16>
__global__ __launch_bounds__(256) void gemm_k(GemmArgs ga){
  GemmDesc dd = ga.d[blockIdx.z];
  int m0 = blockIdx.y * 128;
  if (m0 >= dd.M) return;
  int n0 = blockIdx.x * 128;

  __shared__ __align__(16) __hip_bfloat16 lA[2][128 * 32];
  __shared__ __align__(16) __hip_bfloat16 lB[2][128 * 32];

  int tid = threadIdx.x, lane = tid & 63, wv = tid >> 6;
  int r16 = lane & 15, g = lane >> 4;
  int wr = wv >> 1, wc = wv & 1;

  const __hip_bfloat16* Ab = dd.A + (size_t)m0 * 1024;
  const __hip_bfloat16* Wb = dd.W + (size_t)n0 * 1024;
  int lrow = lane >> 2;
  int scol = (lane & 3) * 8;

  #define STAGE(buf, kc)                                                            \
    {                                                                               \
      _Pragma("unroll")                                                             \
      for (int h = 0; h < 2; ++h){                                                  \
        int rbase = h * 64 + wv * 16;                                               \
        int row = rbase + lrow;                                                     \
        gld_lds16(Ab + (size_t)row * 1024 + (kc) + scol, &lA[buf][rbase * 32]);     \
        gld_lds16(Wb + (size_t)row * 1024 + (kc) + scol, &lB[buf][rbase * 32]);     \
      }                                                                             \
    }

  f32x4 acc[4][4] = {};
  STAGE(0, 0);
  int cur = 0;
  for (int kc = 0; kc < 1024; kc += 32){
    if (kc + 32 < 1024) STAGE(cur ^ 1, kc + 32);
    __syncthreads();
    const __hip_bfloat16* la = &lA[cur][(wr * 64) * 32];
    const __hip_bfloat16* lb = &lB[cur][(wc * 64) * 32];
    short8 af[4], bfr[4];
    #pragma unroll
    for (int t = 0; t < 4; ++t){
      af[t]  = *(const short8*)(la + (t * 16 + r16) * 32 + g * 8);
      bfr[t] = *(const short8*)(lb + (t * 16 + r16) * 32 + g * 8);
    }
    #pragma unroll
    for (int mt = 0; mt < 4; ++mt)
      #pragma unroll
      for (int nt = 0; nt < 4; ++nt)
        acc[mt][nt] = mfma16(af[mt], bfr[nt], acc[mt][nt]);
    __syncthreads();
    cur ^= 1;
  }
  #undef STAGE

  #pragma unroll
  for (int nt = 0; nt < 4; ++nt){
    int col = n0 + wc * 64 + nt * 16 + r16;
    float bb = dd.bias[col];
    #pragma unroll
    for (int mt = 0; mt < 4; ++mt){
      int row0 = m0 + wr * 64 + mt * 16 + g * 4;
      #pragma unroll
      for (int r = 0; r < 4; ++r){
        float v = (acc[mt][nt][r] + bb) * dd.scale;
        if (OUT_BF16) ((__hip_bfloat16*)dd.out)[(size_t)(row0 + r) * 1024 + col] = __float2bfloat16(v);
        else          ((float*)dd.out)[(size_t)(row0 + r) * 1024 + col] = v;
      }
    }
  }
}

// ---------------- fused attention v7 base, template-ablated for diagnosis ----------------
// V=0: full (real output).  V=1: no attn store sweep.  V=3: no Q/K loads, no QK^T
// MFMA (s = mask).  V=4: copy-only (mask->LDS->attn), no compute.
// Probes (V=1,3,4) run BEFORE the real V=0 dispatch and write to the same
// buffers, which V=0 then overwrites -> correctness preserved, deterministic.
template<int L, int V>
__global__ __launch_bounds__(512, 4) void attn_k(
    const __hip_bfloat16* __restrict__ qb, const __hip_bfloat16* __restrict__ kb,
    const __hip_bfloat16* __restrict__ vt, const float* __restrict__ mask,
    float* __restrict__ attn, __hip_bfloat16* __restrict__ ctx){
  constexpr int KQ = L / 8, KT = KQ / 16, CH = KQ / 32;
  constexpr int STR = L + 4;
  constexpr int RQ = L / 4;
  constexpr int SWEEPS = 16 * RQ / 512;
  extern __shared__ __align__(16) float buf[];
  __shared__ float redm[8][16], redl[8][16];

  int bh = blockIdx.y;
  int q0 = blockIdx.x * 16;
  int tid = threadIdx.x;
  int lane = tid & 63, kq = tid >> 6;
  int r16 = lane & 15, g = lane >> 4;
  size_t ho = (size_t)bh * L * 64;
  const __hip_bfloat16* Qp = qb + ho;
  const __hip_bfloat16* Kp = kb + ho + (size_t)kq * KQ * 64;
  const __hip_bfloat16* Vp = vt + ho;
  const float* mbase = mask + (size_t)bh * L * L + (size_t)q0 * L;
  float* abase = attn + (size_t)bh * L * L + (size_t)q0 * L;

  // ---- stage mask tile (coalesced sweeps) ----
  #pragma unroll
  for (int it = 0; it < SWEEPS; ++it){
    int f = tid + it * 512;
    int row = f / RQ, colv = f % RQ;
    *(f32x4*)(buf + row * STR + colv * 4) = *(const f32x4*)(mbase + (size_t)row * L + colv * 4);
  }

  if constexpr (V == 4){
    // copy-only probe: pure stream ceiling of this structure
    __syncthreads();
    #pragma unroll
    for (int it = 0; it < SWEEPS; ++it){
      int f = tid + it * 512;
      int row = f / RQ, colv = f % RQ;
      *(f32x4*)(abase + (size_t)row * L + colv * 4) = *(const f32x4*)(buf + row * STR + colv * 4);
    }
    return;
  } else {

  int q = q0 + r16;
  short8 qf0, qf1;
  if constexpr (V != 3){
    qf0 = *(const short8*)(Qp + (size_t)q * 64 + g * 8);
    qf1 = *(const short8*)(Qp + (size_t)q * 64 + 32 + g * 8);
  }
  __syncthreads();

  // ---- S^T = K @ Q^T (scale folded into Q), mask from LDS ----
  f32x4 s[KT];
  #pragma unroll
  for (int kt = 0; kt < KT; ++kt){
    f32x4 mv = *(const f32x4*)(buf + r16 * STR + kq * KQ + kt * 16 + g * 4);
    if constexpr (V == 3){
      s[kt] = mv;                       // probe: no K loads / no MFMA
    } else {
      const __hip_bfloat16* kr = Kp + (size_t)(kt * 16 + r16) * 64 + g * 8;
      short8 kf0 = *(const short8*)kr;
      short8 kf1 = *(const short8*)(kr + 32);
      f32x4 t = {};
      t = mfma16(kf0, qf0, t);
      t = mfma16(kf1, qf1, t);
      t[0] *= mv[0]; t[1] *= mv[1]; t[2] *= mv[2]; t[3] *= mv[3];
      s[kt] = t;
    }
  }

  // ---- softmax over full k (8 eighths) ----
  float mx = -3.0e38f;
  #pragma unroll
  for (int kt = 0; kt < KT; ++kt)
    #pragma unroll
    for (int r = 0; r < 4; ++r) mx = fmaxf(mx, s[kt][r]);
  mx = fmaxf(mx, __shfl_xor(mx, 16));
  mx = fmaxf(mx, __shfl_xor(mx, 32));
  if (lane < 16) redm[kq][lane] = mx;
  __syncthreads();
  mx = fmaxf(fmaxf(fmaxf(redm[0][r16], redm[1][r16]), fmaxf(redm[2][r16], redm[3][r16])),
             fmaxf(fmaxf(redm[4][r16], redm[5][r16]), fmaxf(redm[6][r16], redm[7][r16])));
  float sm = 0.f;
  #pragma unroll
  for (int kt = 0; kt < KT; ++kt)
    #pragma unroll
    for (int r = 0; r < 4; ++r){ float e = __expf(s[kt][r] - mx); s[kt][r] = e; sm += e; }
  sm += __shfl_xor(sm, 16);
  sm += __shfl_xor(sm, 32);
  if (lane < 16) redl[kq][lane] = sm;
  __syncthreads();
  sm = ((redl[0][r16] + redl[1][r16]) + (redl[2][r16] + redl[3][r16])) +
       ((redl[4][r16] + redl[5][r16]) + (redl[6][r16] + redl[7][r16]));
  float inv = 1.0f / sm;

  // ---- write normalized P into the tile ----
  #pragma unroll
  for (int kt = 0; kt < KT; ++kt){
    f32x4 v;
    v[0] = s[kt][0] * inv; v[1] = s[kt][1] * inv;
    v[2] = s[kt][2] * inv; v[3] = s[kt][3] * inv;
    *(f32x4*)(buf + r16 * STR + kq * KQ + kt * 16 + g * 4) = v;
  }
  __syncthreads();

  // ---- coalesced attn store from LDS (skipped in V=1 probe) ----
  if constexpr (V != 1){
    #pragma unroll
    for (int it = 0; it < SWEEPS; ++it){
      int f = tid + it * 512;
      int row = f / RQ, colv = f % RQ;
      *(f32x4*)(abase + (size_t)row * L + colv * 4) = *(const f32x4*)(buf + row * STR + colv * 4);
    }
  }

  // ---- PV partial over this k-eighth ----
  f32x4 c4[4] = {};
  const __hip_bfloat16* vbase = Vp + kq * KQ;
  #pragma unroll
  for (int ch = 0; ch < CH; ++ch){
    const float* pp = buf + r16 * STR + kq * KQ + ch * 32 + g * 8;
    f32x4 p0 = *(const f32x4*)pp;
    f32x4 p1 = *(const f32x4*)(pp + 4);
    BF8 pk;
    pk.h[0] = __float2bfloat16(p0[0]); pk.h[1] = __float2bfloat16(p0[1]);
    pk.h[2] = __float2bfloat16(p0[2]); pk.h[3] = __float2bfloat16(p0[3]);
    pk.h[4] = __float2bfloat16(p1[0]); pk.h[5] = __float2bfloat16(p1[1]);
    pk.h[6] = __float2bfloat16(p1[2]); pk.h[7] = __float2bfloat16(p1[3]);
    const __hip_bfloat16* vpp = vbase + ch * 32 + g * 8;
    #pragma unroll
    for (int nt = 0; nt < 4; ++nt){
      short8 vf = *(const short8*)(vpp + (size_t)(nt * 16 + r16) * L);
      c4[nt] = mfma16(pk.v, vf, c4[nt]);
    }
  }
  __syncthreads();

  // ---- combine 8 partials via ctxl aliased into buf, write ctx ----
  #pragma unroll
  for (int nt = 0; nt < 4; ++nt)
    #pragma unroll
    for (int r = 0; r < 4; ++r)
      buf[(kq * 16 + g * 4 + r) * 65 + nt * 16 + r16] = c4[nt][r];
  __syncthreads();
  if (kq < 4){
    int dq = kq * 16 + g * 4;
    union { uint64_t u; __hip_bfloat16 h[4]; } ov;
    #pragma unroll
    for (int rr = 0; rr < 4; ++rr){
      float v = ((buf[(0 * 16 + r16) * 65 + dq + rr] + buf[(1 * 16 + r16) * 65 + dq + rr]) +
                 (buf[(2 * 16 + r16) * 65 + dq + rr] + buf[(3 * 16 + r16) * 65 + dq + rr])) +
                ((buf[(4 * 16 + r16) * 65 + dq + rr] + buf[(5 * 16 + r16) * 65 + dq + rr]) +
                 (buf[(6 * 16 + r16) * 65 + dq + rr] + buf[(7 * 16 + r16) * 65 + dq + rr]));
      ov.h[rr] = __float2bfloat16(v);
    }
    *(uint64_t*)(ctx + ho + (size_t)(q0 + r16) * 64 + dq) = ov.u;
  }
  }
}

typedef void (*attn_fn)(const __hip_bfloat16*, const __hip_bfloat16*,
                        const __hip_bfloat16*, const float*, float*, __hip_bfloat16*);

// ---------------- launch ----------------
extern "C" void kernel_launch(void* const* d_in, const int* in_sizes, int n_in,
                              void* d_out, int out_size, void* d_ws, size_t ws_size,
                              hipStream_t stream){
  const float* word_mask = (const float*)d_in[4];
  const float* sent_mask = (const float*)d_in[5];

  char* ws = (char*)d_ws;
  const size_t MB = 1048576;
  __hip_bfloat16* Wt   = (__hip_bfloat16*)(ws);             // 8 x 1024x1024 bf16 (16 MB)
  __hip_bfloat16* bwi  = (__hip_bfloat16*)(ws + 16 * MB);
  __hip_bfloat16* bwc  = (__hip_bfloat16*)(ws + 20 * MB);
  __hip_bfloat16* bsi  = (__hip_bfloat16*)(ws + 24 * MB);
  __hip_bfloat16* bsc  = (__hip_bfloat16*)(ws + 25 * MB);
  __hip_bfloat16* qw   = (__hip_bfloat16*)(ws + 26 * MB);
  __hip_bfloat16* kw   = (__hip_bfloat16*)(ws + 30 * MB);
  __hip_bfloat16* vw   = (__hip_bfloat16*)(ws + 34 * MB);
  __hip_bfloat16* sqb  = (__hip_bfloat16*)(ws + 38 * MB);
  __hip_bfloat16* skb  = (__hip_bfloat16*)(ws + 39 * MB);
  __hip_bfloat16* svb  = (__hip_bfloat16*)(ws + 40 * MB);
  __hip_bfloat16* vtw  = (__hip_bfloat16*)(ws + 41 * MB);
  __hip_bfloat16* vts  = (__hip_bfloat16*)(ws + 45 * MB);
  __hip_bfloat16* ctxw = (__hip_bfloat16*)(ws + 46 * MB);
  __hip_bfloat16* ctxs = (__hip_bfloat16*)(ws + 50 * MB);

  float* out = (float*)d_out;
  float* word_out  = out;
  float* sent_out  = out + 2097152;
  float* word_attn = out + 2621440;
  float* sent_attn = out + 36175872;

  PrepWArgs pw;
  pw.src[0] = (const float*)d_in[6];  pw.src[1] = (const float*)d_in[8];
  pw.src[2] = (const float*)d_in[10]; pw.src[3] = (const float*)d_in[12];
  pw.src[4] = (const float*)d_in[14]; pw.src[5] = (const float*)d_in[16];
  pw.src[6] = (const float*)d_in[18]; pw.src[7] = (const float*)d_in[20];
  prep_w_k<<<dim3(16, 16, 8), 256, 0, stream>>>(pw, Wt);

  CvtArgs cv;
  cv.src[0] = (const float*)d_in[0]; cv.dst[0] = bwi; cv.n[0] = 2097152;
  cv.src[1] = (const float*)d_in[1]; cv.dst[1] = bwc; cv.n[1] = 2097152;
  cv.src[2] = (const float*)d_in[2]; cv.dst[2] = bsi; cv.n[2] = 524288;
  cv.src[3] = (const float*)d_in[3]; cv.dst[3] = bsc; cv.n[3] = 524288;
  cvt_k<<<dim3(1024, 1, 4), 256, 0, stream>>>(cv);

  GemmArgs g1;
  g1.d[0] = { bwi, Wt + (size_t)0 * 1048576, (const float*)d_in[7],  qw,  2048, 1.0f / 32.0f };
  g1.d[1] = { bwc, Wt + (size_t)1 * 1048576, (const float*)d_in[9],  kw,  2048, 1.0f };
  g1.d[2] = { bwc, Wt + (size_t)2 * 1048576, (const float*)d_in[11], vw,  2048, 1.0f };
  g1.d[3] = { bsi, Wt + (size_t)4 * 1048576, (const float*)d_in[15], sqb, 512,  1.0f / 32.0f };
  g1.d[4] = { bsc, Wt + (size_t)5 * 1048576, (const float*)d_in[17], skb, 512,  1.0f };
  g1.d[5] = { bsc, Wt + (size_t)6 * 1048576, (const float*)d_in[19], svb, 512,  1.0f };
  gemm_k<true><<<dim3(8, 16, 6), 256, 0, stream>>>(g1);

  prep_v_k<<<dim3(16, 32, 2), 256, 0, stream>>>(vw, svb, vtw, vts);

  const int shw = 16 * (1024 + 4) * 4;    // 65792 B
  const int shs = 8 * 16 * 65 * 4;        // 33280 B
  hipFuncSetAttribute((const void*)(attn_fn)attn_k<1024, 0>, hipFuncAttributeMaxDynamicSharedMemorySize, shw);
  hipFuncSetAttribute((const void*)(attn_fn)attn_k<1024, 1>, hipFuncAttributeMaxDynamicSharedMemorySize, shw);
  hipFuncSetAttribute((const void*)(attn_fn)attn_k<1024, 3>, hipFuncAttributeMaxDynamicSharedMemorySize, shw);
  hipFuncSetAttribute((const void*)(attn_fn)attn_k<1024, 4>, hipFuncAttributeMaxDynamicSharedMemorySize, shw);

  // ---- diagnostic probes (outputs overwritten by the real V0 dispatch below) ----
  attn_k<1024, 4><<<dim3(64, 32), 512, shw, stream>>>(qw, kw, vtw, word_mask, word_attn, ctxw);
  attn_k<1024, 3><<<dim3(64, 32), 512, shw, stream>>>(qw, kw, vtw, word_mask, word_attn, ctxw);
  attn_k<1024, 1><<<dim3(64, 32), 512, shw, stream>>>(qw, kw, vtw, word_mask, word_attn, ctxw);

  // ---- real kernels ----
  attn_k<1024, 0><<<dim3(64, 32), 512, shw, stream>>>(qw, kw, vtw, word_mask, word_attn, ctxw);
  attn_k<256, 0><<<dim3(16, 32), 512, shs, stream>>>(sqb, skb, vts, sent_mask, sent_attn, ctxs);

  GemmArgs g2 = {};
  g2.d[0] = { ctxw, Wt + (size_t)3 * 1048576, (const float*)d_in[13], word_out, 2048, 1.0f };
  g2.d[1] = { ctxs, Wt + (size_t)7 * 1048576, (const float*)d_in[21], sent_out, 512,  1.0f };
  gemm_k<false><<<dim3(8, 16, 2), 256, 0, stream>>>(g2);
}

// Round 10
// 176.229 us; speedup vs baseline: 2.1243x; 2.1243x over previous
//
#include <hip/hip_runtime.h>
#include <hip/hip_bf16.h>
#include <stdint.h>

typedef __attribute__((ext_vector_type(8))) short short8;
typedef __attribute__((ext_vector_type(4))) float f32x4;

__device__ __forceinline__ f32x4 mfma16(short8 a, short8 b, f32x4 c){
  return __builtin_amdgcn_mfma_f32_16x16x32_bf16(a, b, c, 0, 0, 0);
}

union BF8 { short8 v; __hip_bfloat16 h[8]; };

__device__ __forceinline__ void gld_lds16(const void* g, void* l){
  __builtin_amdgcn_global_load_lds((const __attribute__((address_space(1))) void*)g,
                                   (__attribute__((address_space(3))) void*)l, 16, 0, 0);
}

struct GemmDesc { const __hip_bfloat16* A; const __hip_bfloat16* W; const float* bias; void* out; int M; float scale; };
struct GemmArgs { GemmDesc d[6]; };
struct PrepWArgs { const float* src[8]; };
struct CvtArgs { const float* src[4]; __hip_bfloat16* dst[4]; int n[4]; };

// ---------------- f32 -> bf16 elementwise convert ----------------
__global__ __launch_bounds__(256) void cvt_k(CvtArgs c){
  int z = blockIdx.z;
  int n = c.n[z];
  int i = (blockIdx.x * 256 + threadIdx.x) * 8;
  if (i >= n) return;
  const float4* s = (const float4*)(c.src[z] + i);
  float4 u0 = s[0], u1 = s[1];
  BF8 cv;
  cv.h[0] = __float2bfloat16(u0.x); cv.h[1] = __float2bfloat16(u0.y);
  cv.h[2] = __float2bfloat16(u0.z); cv.h[3] = __float2bfloat16(u0.w);
  cv.h[4] = __float2bfloat16(u1.x); cv.h[5] = __float2bfloat16(u1.y);
  cv.h[6] = __float2bfloat16(u1.z); cv.h[7] = __float2bfloat16(u1.w);
  *(short8*)(c.dst[z] + i) = cv.v;
}

// ---------------- weight transpose + cast: Wt[n][k] = bf16(W[k][n]) ----------------
__global__ __launch_bounds__(256) void prep_w_k(PrepWArgs pa, __hip_bfloat16* dst){
  __shared__ float t[64][65];
  const float* W = pa.src[blockIdx.z];
  int k0 = blockIdx.y * 64, n0 = blockIdx.x * 64;
  int c = threadIdx.x & 63, r0 = (threadIdx.x >> 6) * 16;
  #pragma unroll
  for (int i = 0; i < 16; ++i) t[r0 + i][c] = W[(size_t)(k0 + r0 + i) * 1024 + n0 + c];
  __syncthreads();
  __hip_bfloat16* D = dst + (size_t)blockIdx.z * 1048576;
  #pragma unroll
  for (int i = 0; i < 16; ++i) D[(size_t)(n0 + r0 + i) * 1024 + k0 + c] = __float2bfloat16(t[c][r0 + i]);
}

// ---------------- V transpose (bf16): Vt[bh][d][l] = v[bh][l][d] ----------------
__global__ __launch_bounds__(256) void prep_v_k(const __hip_bfloat16* vw, const __hip_bfloat16* vs,
                                                __hip_bfloat16* vtw, __hip_bfloat16* vts){
  bool word = (blockIdx.z == 0);
  int L = word ? 1024 : 256;
  if (!word && blockIdx.x >= 4) return;
  __shared__ __hip_bfloat16 t[64][65];
  const __hip_bfloat16* src = (word ? vw : vs) + (size_t)blockIdx.y * L * 64;
  __hip_bfloat16* dst = (word ? vtw : vts) + (size_t)blockIdx.y * L * 64;
  int l0 = blockIdx.x * 64;
  int c = threadIdx.x & 63, r0 = (threadIdx.x >> 6) * 16;
  #pragma unroll
  for (int i = 0; i < 16; ++i) t[r0 + i][c] = src[(size_t)(l0 + r0 + i) * 64 + c];
  __syncthreads();
  #pragma unroll
  for (int i = 0; i < 16; ++i) dst[(size_t)(r0 + i) * L + l0 + c] = t[c][r0 + i];
}

// ---------------- batched GEMM, m97 structure (unchanged) ----------------
template<bool OUT_BF16>
__global__ __launch_bounds__(256) void gemm_k(GemmArgs ga){
  GemmDesc dd = ga.d[blockIdx.z];
  int m0 = blockIdx.y * 128;
  if (m0 >= dd.M) return;
  int n0 = blockIdx.x * 128;

  __shared__ __align__(16) __hip_bfloat16 lA[2][128 * 32];
  __shared__ __align__(16) __hip_bfloat16 lB[2][128 * 32];

  int tid = threadIdx.x, lane = tid & 63, wv = tid >> 6;
  int r16 = lane & 15, g = lane >> 4;
  int wr = wv >> 1, wc = wv & 1;

  const __hip_bfloat16* Ab = dd.A + (size_t)m0 * 1024;
  const __hip_bfloat16* Wb = dd.W + (size_t)n0 * 1024;
  int lrow = lane >> 2;
  int scol = (lane & 3) * 8;

  #define STAGE(buf, kc)                                                            \
    {                                                                               \
      _Pragma("unroll")                                                             \
      for (int h = 0; h < 2; ++h){                                                  \
        int rbase = h * 64 + wv * 16;                                               \
        int row = rbase + lrow;                                                     \
        gld_lds16(Ab + (size_t)row * 1024 + (kc) + scol, &lA[buf][rbase * 32]);     \
        gld_lds16(Wb + (size_t)row * 1024 + (kc) + scol, &lB[buf][rbase * 32]);     \
      }                                                                             \
    }

  f32x4 acc[4][4] = {};
  STAGE(0, 0);
  int cur = 0;
  for (int kc = 0; kc < 1024; kc += 32){
    if (kc + 32 < 1024) STAGE(cur ^ 1, kc + 32);
    __syncthreads();
    const __hip_bfloat16* la = &lA[cur][(wr * 64) * 32];
    const __hip_bfloat16* lb = &lB[cur][(wc * 64) * 32];
    short8 af[4], bfr[4];
    #pragma unroll
    for (int t = 0; t < 4; ++t){
      af[t]  = *(const short8*)(la + (t * 16 + r16) * 32 + g * 8);
      bfr[t] = *(const short8*)(lb + (t * 16 + r16) * 32 + g * 8);
    }
    #pragma unroll
    for (int mt = 0; mt < 4; ++mt)
      #pragma unroll
      for (int nt = 0; nt < 4; ++nt)
        acc[mt][nt] = mfma16(af[mt], bfr[nt], acc[mt][nt]);
    __syncthreads();
    cur ^= 1;
  }
  #undef STAGE

  #pragma unroll
  for (int nt = 0; nt < 4; ++nt){
    int col = n0 + wc * 64 + nt * 16 + r16;
    float bb = dd.bias[col];
    #pragma unroll
    for (int mt = 0; mt < 4; ++mt){
      int row0 = m0 + wr * 64 + mt * 16 + g * 4;
      #pragma unroll
      for (int r = 0; r < 4; ++r){
        float v = (acc[mt][nt][r] + bb) * dd.scale;
        if (OUT_BF16) ((__hip_bfloat16*)dd.out)[(size_t)(row0 + r) * 1024 + col] = __float2bfloat16(v);
        else          ((float*)dd.out)[(size_t)(row0 + r) * 1024 + col] = v;
      }
    }
  }
}

// ---------------- fused attention v10: r7 structure + nontemporal attn store ----------------
// r9 ablation: copy-only probe == full kernel == ~90us, 2.7 TB/s -> stream-capped, not
// compute. V0 ran 17% faster when the mask was read by the preceding probe -> L3 thrash:
// per replay, mask read (134MB) + attn write alloc (135MB) exceed 256MB L3, so the mask
// is always cold. Fix: nontemporal on the COALESCED full-line attn store sweep only
// (r6's nt inflation came from scattered 64B stores). Read set then fits L3 across
// replays; mask reads become L3 hits.
template<int L>
__global__ __launch_bounds__(512, 4) void attn_k(
    const __hip_bfloat16* __restrict__ qb, const __hip_bfloat16* __restrict__ kb,
    const __hip_bfloat16* __restrict__ vt, const float* __restrict__ mask,
    float* __restrict__ attn, __hip_bfloat16* __restrict__ ctx){
  constexpr int KQ = L / 8, KT = KQ / 16, CH = KQ / 32;
  constexpr int STR = L + 4;
  constexpr int RQ = L / 4;
  constexpr int SWEEPS = 16 * RQ / 512;
  extern __shared__ __align__(16) float buf[];
  __shared__ float redm[8][16], redl[8][16];

  int bh = blockIdx.y;
  int q0 = blockIdx.x * 16;
  int tid = threadIdx.x;
  int lane = tid & 63, kq = tid >> 6;
  int r16 = lane & 15, g = lane >> 4;
  size_t ho = (size_t)bh * L * 64;
  const __hip_bfloat16* Qp = qb + ho;
  const __hip_bfloat16* Kp = kb + ho + (size_t)kq * KQ * 64;
  const __hip_bfloat16* Vp = vt + ho;
  const float* mbase = mask + (size_t)bh * L * L + (size_t)q0 * L;
  float* abase = attn + (size_t)bh * L * L + (size_t)q0 * L;

  // ---- stage mask tile (coalesced sweeps) ----
  #pragma unroll
  for (int it = 0; it < SWEEPS; ++it){
    int f = tid + it * 512;
    int row = f / RQ, colv = f % RQ;
    *(f32x4*)(buf + row * STR + colv * 4) = *(const f32x4*)(mbase + (size_t)row * L + colv * 4);
  }

  int q = q0 + r16;
  short8 qf0 = *(const short8*)(Qp + (size_t)q * 64 + g * 8);
  short8 qf1 = *(const short8*)(Qp + (size_t)q * 64 + 32 + g * 8);
  __syncthreads();

  // ---- S^T = K @ Q^T (scale folded into Q), mask from LDS ----
  f32x4 s[KT];
  #pragma unroll
  for (int kt = 0; kt < KT; ++kt){
    const __hip_bfloat16* kr = Kp + (size_t)(kt * 16 + r16) * 64 + g * 8;
    short8 kf0 = *(const short8*)kr;
    short8 kf1 = *(const short8*)(kr + 32);
    f32x4 t = {};
    t = mfma16(kf0, qf0, t);
    t = mfma16(kf1, qf1, t);
    f32x4 mv = *(const f32x4*)(buf + r16 * STR + kq * KQ + kt * 16 + g * 4);
    t[0] *= mv[0]; t[1] *= mv[1]; t[2] *= mv[2]; t[3] *= mv[3];
    s[kt] = t;
  }

  // ---- softmax over full k (8 eighths) ----
  float mx = -3.0e38f;
  #pragma unroll
  for (int kt = 0; kt < KT; ++kt)
    #pragma unroll
    for (int r = 0; r < 4; ++r) mx = fmaxf(mx, s[kt][r]);
  mx = fmaxf(mx, __shfl_xor(mx, 16));
  mx = fmaxf(mx, __shfl_xor(mx, 32));
  if (lane < 16) redm[kq][lane] = mx;
  __syncthreads();
  mx = fmaxf(fmaxf(fmaxf(redm[0][r16], redm[1][r16]), fmaxf(redm[2][r16], redm[3][r16])),
             fmaxf(fmaxf(redm[4][r16], redm[5][r16]), fmaxf(redm[6][r16], redm[7][r16])));
  float sm = 0.f;
  #pragma unroll
  for (int kt = 0; kt < KT; ++kt)
    #pragma unroll
    for (int r = 0; r < 4; ++r){ float e = __expf(s[kt][r] - mx); s[kt][r] = e; sm += e; }
  sm += __shfl_xor(sm, 16);
  sm += __shfl_xor(sm, 32);
  if (lane < 16) redl[kq][lane] = sm;
  __syncthreads();
  sm = ((redl[0][r16] + redl[1][r16]) + (redl[2][r16] + redl[3][r16])) +
       ((redl[4][r16] + redl[5][r16]) + (redl[6][r16] + redl[7][r16]));
  float inv = 1.0f / sm;

  // ---- write normalized P into the tile ----
  #pragma unroll
  for (int kt = 0; kt < KT; ++kt){
    f32x4 v;
    v[0] = s[kt][0] * inv; v[1] = s[kt][1] * inv;
    v[2] = s[kt][2] * inv; v[3] = s[kt][3] * inv;
    *(f32x4*)(buf + r16 * STR + kq * KQ + kt * 16 + g * 4) = v;
  }
  __syncthreads();

  // ---- coalesced attn store from LDS -- NONTEMPORAL (full-line, no alloc) ----
  #pragma unroll
  for (int it = 0; it < SWEEPS; ++it){
    int f = tid + it * 512;
    int row = f / RQ, colv = f % RQ;
    f32x4 v = *(const f32x4*)(buf + row * STR + colv * 4);
    __builtin_nontemporal_store(v, (f32x4*)(abase + (size_t)row * L + colv * 4));
  }

  // ---- PV partial over this k-eighth ----
  f32x4 c4[4] = {};
  const __hip_bfloat16* vbase = Vp + kq * KQ;
  #pragma unroll
  for (int ch = 0; ch < CH; ++ch){
    const float* pp = buf + r16 * STR + kq * KQ + ch * 32 + g * 8;
    f32x4 p0 = *(const f32x4*)pp;
    f32x4 p1 = *(const f32x4*)(pp + 4);
    BF8 pk;
    pk.h[0] = __float2bfloat16(p0[0]); pk.h[1] = __float2bfloat16(p0[1]);
    pk.h[2] = __float2bfloat16(p0[2]); pk.h[3] = __float2bfloat16(p0[3]);
    pk.h[4] = __float2bfloat16(p1[0]); pk.h[5] = __float2bfloat16(p1[1]);
    pk.h[6] = __float2bfloat16(p1[2]); pk.h[7] = __float2bfloat16(p1[3]);
    const __hip_bfloat16* vpp = vbase + ch * 32 + g * 8;
    #pragma unroll
    for (int nt = 0; nt < 4; ++nt){
      short8 vf = *(const short8*)(vpp + (size_t)(nt * 16 + r16) * L);
      c4[nt] = mfma16(pk.v, vf, c4[nt]);
    }
  }
  __syncthreads();

  // ---- combine 8 partials via ctxl aliased into buf, write ctx ----
  #pragma unroll
  for (int nt = 0; nt < 4; ++nt)
    #pragma unroll
    for (int r = 0; r < 4; ++r)
      buf[(kq * 16 + g * 4 + r) * 65 + nt * 16 + r16] = c4[nt][r];
  __syncthreads();
  if (kq < 4){
    int dq = kq * 16 + g * 4;
    union { uint64_t u; __hip_bfloat16 h[4]; } ov;
    #pragma unroll
    for (int rr = 0; rr < 4; ++rr){
      float v = ((buf[(0 * 16 + r16) * 65 + dq + rr] + buf[(1 * 16 + r16) * 65 + dq + rr]) +
                 (buf[(2 * 16 + r16) * 65 + dq + rr] + buf[(3 * 16 + r16) * 65 + dq + rr])) +
                ((buf[(4 * 16 + r16) * 65 + dq + rr] + buf[(5 * 16 + r16) * 65 + dq + rr]) +
                 (buf[(6 * 16 + r16) * 65 + dq + rr] + buf[(7 * 16 + r16) * 65 + dq + rr]));
      ov.h[rr] = __float2bfloat16(v);
    }
    *(uint64_t*)(ctx + ho + (size_t)(q0 + r16) * 64 + dq) = ov.u;
  }
}

typedef void (*attn_fn)(const __hip_bfloat16*, const __hip_bfloat16*,
                        const __hip_bfloat16*, const float*, float*, __hip_bfloat16*);

// ---------------- launch ----------------
extern "C" void kernel_launch(void* const* d_in, const int* in_sizes, int n_in,
                              void* d_out, int out_size, void* d_ws, size_t ws_size,
                              hipStream_t stream){
  const float* word_mask = (const float*)d_in[4];
  const float* sent_mask = (const float*)d_in[5];

  char* ws = (char*)d_ws;
  const size_t MB = 1048576;
  __hip_bfloat16* Wt   = (__hip_bfloat16*)(ws);             // 8 x 1024x1024 bf16 (16 MB)
  __hip_bfloat16* bwi  = (__hip_bfloat16*)(ws + 16 * MB);
  __hip_bfloat16* bwc  = (__hip_bfloat16*)(ws + 20 * MB);
  __hip_bfloat16* bsi  = (__hip_bfloat16*)(ws + 24 * MB);
  __hip_bfloat16* bsc  = (__hip_bfloat16*)(ws + 25 * MB);
  __hip_bfloat16* qw   = (__hip_bfloat16*)(ws + 26 * MB);
  __hip_bfloat16* kw   = (__hip_bfloat16*)(ws + 30 * MB);
  __hip_bfloat16* vw   = (__hip_bfloat16*)(ws + 34 * MB);
  __hip_bfloat16* sqb  = (__hip_bfloat16*)(ws + 38 * MB);
  __hip_bfloat16* skb  = (__hip_bfloat16*)(ws + 39 * MB);
  __hip_bfloat16* svb  = (__hip_bfloat16*)(ws + 40 * MB);
  __hip_bfloat16* vtw  = (__hip_bfloat16*)(ws + 41 * MB);
  __hip_bfloat16* vts  = (__hip_bfloat16*)(ws + 45 * MB);
  __hip_bfloat16* ctxw = (__hip_bfloat16*)(ws + 46 * MB);
  __hip_bfloat16* ctxs = (__hip_bfloat16*)(ws + 50 * MB);

  float* out = (float*)d_out;
  float* word_out  = out;
  float* sent_out  = out + 2097152;
  float* word_attn = out + 2621440;
  float* sent_attn = out + 36175872;

  PrepWArgs pw;
  pw.src[0] = (const float*)d_in[6];  pw.src[1] = (const float*)d_in[8];
  pw.src[2] = (const float*)d_in[10]; pw.src[3] = (const float*)d_in[12];
  pw.src[4] = (const float*)d_in[14]; pw.src[5] = (const float*)d_in[16];
  pw.src[6] = (const float*)d_in[18]; pw.src[7] = (const float*)d_in[20];
  prep_w_k<<<dim3(16, 16, 8), 256, 0, stream>>>(pw, Wt);

  CvtArgs cv;
  cv.src[0] = (const float*)d_in[0]; cv.dst[0] = bwi; cv.n[0] = 2097152;
  cv.src[1] = (const float*)d_in[1]; cv.dst[1] = bwc; cv.n[1] = 2097152;
  cv.src[2] = (const float*)d_in[2]; cv.dst[2] = bsi; cv.n[2] = 524288;
  cv.src[3] = (const float*)d_in[3]; cv.dst[3] = bsc; cv.n[3] = 524288;
  cvt_k<<<dim3(1024, 1, 4), 256, 0, stream>>>(cv);

  GemmArgs g1;
  g1.d[0] = { bwi, Wt + (size_t)0 * 1048576, (const float*)d_in[7],  qw,  2048, 1.0f / 32.0f };
  g1.d[1] = { bwc, Wt + (size_t)1 * 1048576, (const float*)d_in[9],  kw,  2048, 1.0f };
  g1.d[2] = { bwc, Wt + (size_t)2 * 1048576, (const float*)d_in[11], vw,  2048, 1.0f };
  g1.d[3] = { bsi, Wt + (size_t)4 * 1048576, (const float*)d_in[15], sqb, 512,  1.0f / 32.0f };
  g1.d[4] = { bsc, Wt + (size_t)5 * 1048576, (const float*)d_in[17], skb, 512,  1.0f };
  g1.d[5] = { bsc, Wt + (size_t)6 * 1048576, (const float*)d_in[19], svb, 512,  1.0f };
  gemm_k<true><<<dim3(8, 16, 6), 256, 0, stream>>>(g1);

  prep_v_k<<<dim3(16, 32, 2), 256, 0, stream>>>(vw, svb, vtw, vts);

  const int shw = 16 * (1024 + 4) * 4;    // 65792 B
  const int shs = 8 * 16 * 65 * 4;        // 33280 B
  hipFuncSetAttribute((const void*)(attn_fn)attn_k<1024>, hipFuncAttributeMaxDynamicSharedMemorySize, shw);
  attn_k<1024><<<dim3(64, 32), 512, shw, stream>>>(qw, kw, vtw, word_mask, word_attn, ctxw);
  attn_k<256><<<dim3(16, 32), 512, shs, stream>>>(sqb, skb, vts, sent_mask, sent_attn, ctxs);

  GemmArgs g2 = {};
  g2.d[0] = { ctxw, Wt + (size_t)3 * 1048576, (const float*)d_in[13], word_out, 2048, 1.0f };
  g2.d[1] = { ctxs, Wt + (size_t)7 * 1048576, (const float*)d_in[21], sent_out, 512,  1.0f };
  gemm_k<false><<<dim3(8, 16, 2), 256, 0, stream>>>(g2);
}